// Round 4
// baseline (3976.266 us; speedup 1.0000x reference)
//
#include <hip/hip_runtime.h>

// LSTM decoder, MI355X. Persistent-kernel recurrence with per-XCD L2 staging.
// Sound paths only:
//  - producer h publication: agent-scope write-through stores (MALL)
//  - leader h consumption:   agent-scope atomic loads (MALL-direct, stale-L2-immune)
//  - intra-XCD fanout:       leader cached stores -> own L2 (dirty-fresh beats any
//                            stale/poison copy); followers plain-load same L2 after
//                            buffer_inv sc0 (L1-only invalidate)
//  - cross-kernel plain reads limited to replay-invariant data (actb/wg/pre0/h0f)
// L=128, B=64, IN_F=ACT_F=512, H=1024.

#define LSTEPS 128
#define B 64
#define ACTF 512
#define H 1024
#define NB 128             // persistent blocks, co-resident (1/CU at 104KB LDS)
#define HC 8               // h-columns per block
#define LCOLS 32           // gate columns per block (4 gates x HC)
#define GSTR 33            // LDS gate tile leading-dim pad

typedef short s16x8 __attribute__((ext_vector_type(8)));   // 8 x bf16
typedef float f32x4 __attribute__((ext_vector_type(4)));
typedef unsigned short u16;
typedef unsigned long long u64;

__device__ __forceinline__ u16 f2bf(float f) {
  return __builtin_bit_cast(u16, (__bf16)f);   // RNE
}
__device__ __forceinline__ float sigm(float x) { return 1.f / (1.f + __expf(-x)); }
__device__ __forceinline__ float tanh_fast(float x) { return 2.f / (1.f + __expf(-2.f * x)) - 1.f; }

// ---- merged setup kernel: role by block range ----
__global__ void k_setup(const float* __restrict__ act, u16* __restrict__ actb,
                        const float* __restrict__ Wih, const float* __restrict__ Whh,
                        u16* __restrict__ wg,
                        const float* __restrict__ h0, float* __restrict__ h0f,
                        unsigned* __restrict__ flags, unsigned* __restrict__ xflag,
                        unsigned* __restrict__ xctr,
                        const float* __restrict__ inf, const float* __restrict__ bih,
                        const float* __restrict__ bhh, float* __restrict__ pre0) {
  const int bb = blockIdx.x;
  const int tid = threadIdx.x;
  if (bb < 2048) {                                   // act fp32 -> bf16
    int id = bb * 256 + tid;
    const float4* s = (const float4*)act + (size_t)id * 2;
    float4 a = s[0], b = s[1];
    s16x8 o;
    o[0] = (short)f2bf(a.x); o[1] = (short)f2bf(a.y); o[2] = (short)f2bf(a.z); o[3] = (short)f2bf(a.w);
    o[4] = (short)f2bf(b.x); o[5] = (short)f2bf(b.y); o[6] = (short)f2bf(b.z); o[7] = (short)f2bf(b.w);
    *((s16x8*)actb + id) = o;
  } else if (bb < 5120) {                            // W fragments (B-frag contiguous)
    int idx = (bb - 2048) * 256 + tid;
    int bk = idx / 6144;
    int lin = idx - bk * 6144;
    int kt = lin >> 7, T = (lin >> 6) & 1, lane = lin & 63;
    int q = lane >> 4, r = lane & 15;
    int local = T * 16 + r;
    int j = (local >> 3) * 1024 + bk * 8 + (local & 7);
    int k = kt * 32 + q * 8;
    const float* src = (k < 512) ? (Wih + (size_t)j * 1024 + 512 + k)
                                 : (Whh + (size_t)j * 1024 + (k - 512));
    s16x8 o;
#pragma unroll
    for (int e = 0; e < 8; ++e) o[e] = (short)f2bf(src[e]);
    ((s16x8*)wg)[(size_t)bk * 6144 + lin] = o;
  } else if (bb < 5184) {                            // h0 copy + zero all flags/ctrs
    int id = (bb - 5120) * 256 + tid;
    ((float4*)h0f)[id] = ((const float4*)h0)[id];
    if (bb == 5120 && tid < NB) flags[tid] = 0u;
    if (bb == 5120 && tid < 8) { xflag[tid] = 0u; xctr[tid] = 0u; }
  } else {                                           // PRE0 = IF@Wih[:,:512]^T + b_ih + b_hh
    int o = (bb - 5184) * 256 + tid;
    int bk = o >> 11;
    int rr = o & 2047;
    int b = rr >> 5;
    int local = rr & 31;
    int j = (local >> 3) * 1024 + bk * 8 + (local & 7);
    const float4* xa = (const float4*)(inf + (size_t)b * 512);
    const float4* wa = (const float4*)(Wih + (size_t)j * 1024);
    float s = 0.f;
#pragma unroll 4
    for (int k = 0; k < 128; ++k) {
      float4 x = xa[k], w = wa[k];
      s += x.x * w.x + x.y * w.y + x.z * w.z + x.w * w.w;
    }
    pre0[o] = s + bih[j] + bhh[j];
  }
}

// ---- persistent recurrent kernel ----
__global__ void __launch_bounds__(256, 1) k_rnn(
    const u16* __restrict__ actb, const u16* __restrict__ wg,
    const float* __restrict__ pre0, const float* __restrict__ cinit,
    const float* __restrict__ h0f, unsigned* __restrict__ flags,
    unsigned* __restrict__ xflag, unsigned* __restrict__ xctr,
    u16* __restrict__ stg, float* __restrict__ out) {
  extern __shared__ char smem[];
  u16* wlds = (u16*)smem;                 // 98304 B: W fragments (persistent)
  float* gl = (float*)(smem + 98304);     // 64 x 33 fp32 gate tile
  __shared__ int s_xcc, s_leader;

  const int tid = threadIdx.x;
  const int bk = blockIdx.x;
  const int w = tid >> 6;
  const int lane = tid & 63;
  const int q = lane >> 4, r = lane & 15;
  const int n0 = bk * HC;

  // XCD discovery + leader election (one leader per occupied XCD)
  if (tid == 0) {
    unsigned xcc;
    asm volatile("s_getreg_b32 %0, hwreg(HW_REG_XCC_ID)" : "=s"(xcc));
    xcc &= 7u;
    s_xcc = (int)xcc;
    s_leader = (atomicAdd(&xctr[xcc], 1u) == 0u) ? 1 : 0;
  }

  {
    const s16x8* src = (const s16x8*)wg + (size_t)bk * 6144;
    s16x8* dst = (s16x8*)wlds;
    for (int i = tid; i < 6144; i += 256) dst[i] = src[i];
  }

  // PRE0 slice in registers
  float pr[8];
#pragma unroll
  for (int j = 0; j < 8; ++j) pr[j] = pre0[bk * (B * LCOLS) + j * 256 + tid];

  // pointwise pairing: thread -> (batch b0, adjacent cols c0,c0+1) for 8B stores
  const int b0 = tid >> 2, c0 = (tid & 3) * 2, c1 = c0 + 1;
  float cr0 = cinit[b0 * H + n0 + c0];
  float cr1 = cinit[b0 * H + n0 + c1];

  __syncthreads();
  const int xcc = s_xcc;
  const int leader = s_leader;
  u16* stgx = stg + (size_t)xcc * 2 * 65536;   // this XCD's two parity buffers

  for (int t = 0; t < LSTEPS; ++t) {
    // phase 1: gate tile init from registers
#pragma unroll
    for (int j = 0; j < 8; ++j) {
      int i = j * 256 + tid;
      gl[(i >> 5) * GSTR + (i & 31)] = pr[j];
    }
    __syncthreads();

    f32x4 acc[4][2];
#pragma unroll
    for (int mt = 0; mt < 4; ++mt) {
      f32x4 z = {0.f, 0.f, 0.f, 0.f};
      acc[mt][0] = z; acc[mt][1] = z;
    }

    // phase 2: act-part MFMAs (independent of h(t-1))
    const u16* atb = actb + (size_t)t * (B * ACTF);
#pragma unroll
    for (int kk = 0; kk < 4; ++kk) {
      const int kt = w * 4 + kk;
      const int k = kt * 32 + q * 8;
      const s16x8* wb = (const s16x8*)wlds + kt * 128;
      s16x8 bf0 = wb[lane];
      s16x8 bf1 = wb[64 + lane];
#pragma unroll
      for (int mt = 0; mt < 4; ++mt) {
        const int m = mt * 16 + r;
        s16x8 af = *(const s16x8*)(atb + m * ACTF + k);
        acc[mt][0] = __builtin_amdgcn_mfma_f32_16x16x32_bf16(af, bf0, acc[mt][0], 0, 0, 0);
        acc[mt][1] = __builtin_amdgcn_mfma_f32_16x16x32_bf16(af, bf1, acc[mt][1], 0, 0, 0);
      }
    }

    // phase 3: acquire h(t-1)
    if (t) {
      if (leader) {
        if (tid < NB) {
          unsigned g = 0;
          while (__hip_atomic_load(&flags[tid], __ATOMIC_RELAXED, __HIP_MEMORY_SCOPE_AGENT) < (unsigned)t) {
            __builtin_amdgcn_s_sleep(1);
            if (++g > (1u << 22)) break;   // bounded spin: wrong-answer beats hang
          }
        }
        __syncthreads();
        asm volatile("" ::: "memory");
        // stage h(t-1): MALL atomic reads -> bf16 -> own-XCD L2 cached stores
        const u64* src = (const u64*)(out + (size_t)(t - 1) * (B * H));
        s16x8* dst = (s16x8*)(stgx + ((t - 1) & 1) * 65536);
#pragma unroll 4
        for (int j = 0; j < 32; ++j) {
          int fb = j * 1024 + tid * 4;     // float2 index
          u64 q0 = __hip_atomic_load(src + fb + 0, __ATOMIC_RELAXED, __HIP_MEMORY_SCOPE_AGENT);
          u64 q1 = __hip_atomic_load(src + fb + 1, __ATOMIC_RELAXED, __HIP_MEMORY_SCOPE_AGENT);
          u64 q2 = __hip_atomic_load(src + fb + 2, __ATOMIC_RELAXED, __HIP_MEMORY_SCOPE_AGENT);
          u64 q3 = __hip_atomic_load(src + fb + 3, __ATOMIC_RELAXED, __HIP_MEMORY_SCOPE_AGENT);
          float2 f0 = __builtin_bit_cast(float2, q0);
          float2 f1 = __builtin_bit_cast(float2, q1);
          float2 f2 = __builtin_bit_cast(float2, q2);
          float2 f3 = __builtin_bit_cast(float2, q3);
          s16x8 o;
          o[0] = (short)f2bf(f0.x); o[1] = (short)f2bf(f0.y);
          o[2] = (short)f2bf(f1.x); o[3] = (short)f2bf(f1.y);
          o[4] = (short)f2bf(f2.x); o[5] = (short)f2bf(f2.y);
          o[6] = (short)f2bf(f3.x); o[7] = (short)f2bf(f3.y);
          dst[j * 256 + tid] = o;
        }
        asm volatile("s_waitcnt vmcnt(0)" ::: "memory");
        __syncthreads();
        if (tid == 0)
          __hip_atomic_store(&xflag[xcc], (unsigned)t, __ATOMIC_RELAXED, __HIP_MEMORY_SCOPE_AGENT);
      } else {
        if (tid == 0) {
          unsigned g = 0;
          while (__hip_atomic_load(&xflag[xcc], __ATOMIC_RELAXED, __HIP_MEMORY_SCOPE_AGENT) < (unsigned)t) {
            __builtin_amdgcn_s_sleep(1);
            if (++g > (1u << 22)) break;
          }
        }
        __syncthreads();
        asm volatile("buffer_inv sc0" ::: "memory");  // L1-only invalidate
      }
    }

    // phase 4: h-part MFMAs
    if (t) {
      const u16* hstg = stgx + ((t - 1) & 1) * 65536;
#pragma unroll
      for (int kk = 0; kk < 8; ++kk) {
        const int kt = 16 + w * 8 + kk;
        const int k = kt * 32 + q * 8;
        const s16x8* wb = (const s16x8*)wlds + kt * 128;
        s16x8 bf0 = wb[lane];
        s16x8 bf1 = wb[64 + lane];
#pragma unroll
        for (int mt = 0; mt < 4; ++mt) {
          const int m = mt * 16 + r;
          s16x8 af = *(const s16x8*)(hstg + m * H + (k - ACTF));
          acc[mt][0] = __builtin_amdgcn_mfma_f32_16x16x32_bf16(af, bf0, acc[mt][0], 0, 0, 0);
          acc[mt][1] = __builtin_amdgcn_mfma_f32_16x16x32_bf16(af, bf1, acc[mt][1], 0, 0, 0);
        }
      }
    } else {
      // t=0: h0f is replay-invariant -> plain fp32 loads are sound
#pragma unroll
      for (int kk = 0; kk < 8; ++kk) {
        const int kt = 16 + w * 8 + kk;
        const int k = kt * 32 + q * 8;
        const s16x8* wb = (const s16x8*)wlds + kt * 128;
        s16x8 bf0 = wb[lane];
        s16x8 bf1 = wb[64 + lane];
#pragma unroll
        for (int mt = 0; mt < 4; ++mt) {
          const int m = mt * 16 + r;
          const float* hp = h0f + m * H + (k - ACTF);
          f32x4 x0 = *(const f32x4*)hp;
          f32x4 x1 = *(const f32x4*)(hp + 4);
          s16x8 af;
          af[0] = (short)f2bf(x0[0]); af[1] = (short)f2bf(x0[1]);
          af[2] = (short)f2bf(x0[2]); af[3] = (short)f2bf(x0[3]);
          af[4] = (short)f2bf(x1[0]); af[5] = (short)f2bf(x1[1]);
          af[6] = (short)f2bf(x1[2]); af[7] = (short)f2bf(x1[3]);
          acc[mt][0] = __builtin_amdgcn_mfma_f32_16x16x32_bf16(af, bf0, acc[mt][0], 0, 0, 0);
          acc[mt][1] = __builtin_amdgcn_mfma_f32_16x16x32_bf16(af, bf1, acc[mt][1], 0, 0, 0);
        }
      }
    }

    // phase 5: cross-wave K reduction
#pragma unroll
    for (int mt = 0; mt < 4; ++mt) {
      const int bb2 = mt * 16 + q * 4;
#pragma unroll
      for (int T = 0; T < 2; ++T) {
        const int lc = T * 16 + r;
#pragma unroll
        for (int e = 0; e < 4; ++e)
          atomicAdd(&gl[(bb2 + e) * GSTR + lc], acc[mt][T][e]);
      }
    }
    __syncthreads();

    // phase 6: pointwise LSTM cell (two adjacent cols of one batch row)
    float ig, fg, gg, og, hv0, hv1;
    ig = sigm(gl[b0 * GSTR + c0]);
    fg = sigm(gl[b0 * GSTR + 8 + c0]);
    gg = tanh_fast(gl[b0 * GSTR + 16 + c0]);
    og = sigm(gl[b0 * GSTR + 24 + c0]);
    cr0 = fg * cr0 + ig * gg;
    hv0 = og * tanh_fast(cr0);

    ig = sigm(gl[b0 * GSTR + c1]);
    fg = sigm(gl[b0 * GSTR + 8 + c1]);
    gg = tanh_fast(gl[b0 * GSTR + 16 + c1]);
    og = sigm(gl[b0 * GSTR + 24 + c1]);
    cr1 = fg * cr1 + ig * gg;
    hv1 = og * tanh_fast(cr1);

    // h(t) publication: one paired 8B agent write-through store
    float* op = out + (size_t)t * (B * H);
    float2 hv2 = make_float2(hv0, hv1);
    __hip_atomic_store((u64*)(op + b0 * H + n0 + c0), __builtin_bit_cast(u64, hv2),
                       __ATOMIC_RELAXED, __HIP_MEMORY_SCOPE_AGENT);

    if (t == LSTEPS - 1) {
      float* hn = out + (size_t)LSTEPS * B * H;
      float* cn = hn + B * H;
      hn[b0 * H + n0 + c0] = hv0; hn[b0 * H + n0 + c1] = hv1;
      cn[b0 * H + n0 + c0] = cr0; cn[b0 * H + n0 + c1] = cr1;
    } else {
      asm volatile("s_waitcnt vmcnt(0)" ::: "memory");
      __syncthreads();
      if (tid == 0)
        __hip_atomic_store(&flags[bk], (unsigned)(t + 1), __ATOMIC_RELAXED, __HIP_MEMORY_SCOPE_AGENT);
    }
  }
}

extern "C" void kernel_launch(void* const* d_in, const int* in_sizes, int n_in,
                              void* d_out, int out_size, void* d_ws, size_t ws_size,
                              hipStream_t stream) {
  const float* inf = (const float*)d_in[0];
  const float* act = (const float*)d_in[1];
  const float* h0  = (const float*)d_in[2];
  const float* cst = (const float*)d_in[3];
  const float* Wih = (const float*)d_in[4];
  const float* Whh = (const float*)d_in[5];
  const float* bih = (const float*)d_in[6];
  const float* bhh = (const float*)d_in[7];
  float* out = (float*)d_out;

  char* ws = (char*)d_ws;
  u16* actb      = (u16*)ws;                    //  8,388,608 B
  u16* wg        = (u16*)(ws + 8388608);        // 12,582,912 B
  float* pre0    = (float*)(ws + 20971520);     //  1,048,576 B
  float* h0f     = (float*)(ws + 22020096);     //    262,144 B
  u16* stg       = (u16*)(ws + 22282240);       //  2,097,152 B (8 XCD x 2 parity x 128KB)
  unsigned* flg  = (unsigned*)(ws + 24379392);  //        512 B
  unsigned* xfl  = (unsigned*)(ws + 24379904);  //         64 B
  unsigned* xct  = (unsigned*)(ws + 24379968);  //         64 B

  hipLaunchKernelGGL(k_setup, dim3(6208), dim3(256), 0, stream,
                     act, actb, Wih, Whh, wg, h0, h0f, flg, xfl, xct,
                     inf, bih, bhh, pre0);

  hipFuncSetAttribute((const void*)k_rnn, hipFuncAttributeMaxDynamicSharedMemorySize, 106752);
  hipLaunchKernelGGL(k_rnn, dim3(NB), dim3(256), 106752, stream,
                     actb, wg, pre0, cst, h0f, flg, xfl, xct, stg, out);
}

// Round 5
// 2662.365 us; speedup vs baseline: 1.4935x; 1.4935x over previous
//
#include <hip/hip_runtime.h>

// LSTM decoder, MI355X. Persistent persistent-kernel recurrence, round 5.
// Sync fabric redesign: single monotone global step counter (tid0-only polls),
// 16B sc0/sc1 coherent loads/stores for all cross-XCD data, distributed
// per-XCD staging pull (1/16 slice per block, no leader serialization).
// L=128, B=64, IN_F=ACT_F=512, H=1024.

#define LSTEPS 128
#define B 64
#define ACTF 512
#define H 1024
#define NB 128             // persistent blocks, co-resident (1/CU at ~104KB LDS)
#define HC 8               // h-columns per block
#define LCOLS 32           // gate columns per block (4 gates x HC)
#define GSTR 33            // LDS gate tile leading-dim pad

typedef short s16x8 __attribute__((ext_vector_type(8)));   // 8 x bf16
typedef short s16x4 __attribute__((ext_vector_type(4)));   // 4 x bf16
typedef float f32x4 __attribute__((ext_vector_type(4)));
typedef unsigned short u16;
typedef unsigned long long u64;

__device__ __forceinline__ u16 f2bf(float f) {
  return __builtin_bit_cast(u16, (__bf16)f);   // RNE
}
__device__ __forceinline__ float sigm(float x) { return 1.f / (1.f + __expf(-x)); }
__device__ __forceinline__ float tanh_fast(float x) { return 2.f / (1.f + __expf(-2.f * x)) - 1.f; }

// coherent (stale-L2-immune) 16B load/store — same cache bits the proven
// agent-scope atomics used, but full-width.
__device__ __forceinline__ s16x8 ld16_coh(const void* p) {
  s16x8 v;
  asm volatile("global_load_dwordx4 %0, %1, off sc0 sc1" : "=v"(v) : "v"(p) : "memory");
  return v;
}
__device__ __forceinline__ void st16_coh(void* p, f32x4 v) {
  asm volatile("global_store_dwordx4 %0, %1, off sc0 sc1" :: "v"(p), "v"(v) : "memory");
}
__device__ __forceinline__ void st8_coh(void* p, u64 v) {
  asm volatile("global_store_dwordx2 %0, %1, off sc0 sc1" :: "v"(p), "v"(v) : "memory");
}

// ---- merged setup kernel: role by block range ----
__global__ void k_setup(const float* __restrict__ act, u16* __restrict__ actb,
                        const float* __restrict__ Wih, const float* __restrict__ Whh,
                        u16* __restrict__ wg,
                        const float* __restrict__ h0, u16* __restrict__ hbf,
                        unsigned* __restrict__ scnt, unsigned* __restrict__ xcnt,
                        unsigned* __restrict__ xctr,
                        const float* __restrict__ inf, const float* __restrict__ bih,
                        const float* __restrict__ bhh, float* __restrict__ pre0) {
  const int bb = blockIdx.x;
  const int tid = threadIdx.x;
  if (bb < 2048) {                                   // act fp32 -> bf16
    int id = bb * 256 + tid;
    const float4* s = (const float4*)act + (size_t)id * 2;
    float4 a = s[0], b = s[1];
    s16x8 o;
    o[0] = (short)f2bf(a.x); o[1] = (short)f2bf(a.y); o[2] = (short)f2bf(a.z); o[3] = (short)f2bf(a.w);
    o[4] = (short)f2bf(b.x); o[5] = (short)f2bf(b.y); o[6] = (short)f2bf(b.z); o[7] = (short)f2bf(b.w);
    *((s16x8*)actb + id) = o;
  } else if (bb < 5120) {                            // W fragments (B-frag contiguous)
    int idx = (bb - 2048) * 256 + tid;
    int bk = idx / 6144;
    int lin = idx - bk * 6144;
    int kt = lin >> 7, T = (lin >> 6) & 1, lane = lin & 63;
    int q = lane >> 4, r = lane & 15;
    int local = T * 16 + r;
    int j = (local >> 3) * 1024 + bk * 8 + (local & 7);
    int k = kt * 32 + q * 8;
    const float* src = (k < 512) ? (Wih + (size_t)j * 1024 + 512 + k)
                                 : (Whh + (size_t)j * 1024 + (k - 512));
    s16x8 o;
#pragma unroll
    for (int e = 0; e < 8; ++e) o[e] = (short)f2bf(src[e]);
    ((s16x8*)wg)[(size_t)bk * 6144 + lin] = o;
  } else if (bb < 5152) {                            // h0 -> bf16 into hbf[1] + zero counters
    int id = (bb - 5120) * 256 + tid;                // 0..8191, 8 elems each
    const float4* s = (const float4*)h0 + (size_t)id * 2;
    float4 a = s[0], b = s[1];
    s16x8 o;
    o[0] = (short)f2bf(a.x); o[1] = (short)f2bf(a.y); o[2] = (short)f2bf(a.z); o[3] = (short)f2bf(a.w);
    o[4] = (short)f2bf(b.x); o[5] = (short)f2bf(b.y); o[6] = (short)f2bf(b.z); o[7] = (short)f2bf(b.w);
    *((s16x8*)(hbf + 65536) + id) = o;
    if (bb == 5120) {
      if (tid == 0) scnt[0] = 0u;
      if (tid < 128) xcnt[tid] = 0u;
      if (tid < 8) xctr[tid] = 0u;
    }
  } else {                                           // PRE0 = IF@Wih[:,:512]^T + b_ih + b_hh
    int o = (bb - 5152) * 256 + tid;
    int bk = o >> 11;
    int rr = o & 2047;
    int b = rr >> 5;
    int local = rr & 31;
    int j = (local >> 3) * 1024 + bk * 8 + (local & 7);
    const float4* xa = (const float4*)(inf + (size_t)b * 512);
    const float4* wa = (const float4*)(Wih + (size_t)j * 1024);
    float s = 0.f;
#pragma unroll 4
    for (int k = 0; k < 128; ++k) {
      float4 x = xa[k], w = wa[k];
      s += x.x * w.x + x.y * w.y + x.z * w.z + x.w * w.w;
    }
    pre0[o] = s + bih[j] + bhh[j];
  }
}

// ---- persistent recurrent kernel ----
__global__ void __launch_bounds__(256, 1) k_rnn(
    const u16* __restrict__ actb, const u16* __restrict__ wg,
    const float* __restrict__ pre0, const float* __restrict__ cinit,
    u16* __restrict__ hbf, u16* __restrict__ stg,
    unsigned* __restrict__ scnt, unsigned* __restrict__ xcnt,
    unsigned* __restrict__ xctr, float* __restrict__ out) {
  extern __shared__ char smem[];
  u16* wlds = (u16*)smem;                 // 98304 B: W fragments (persistent)
  float* gl = (float*)(smem + 98304);     // 64 x 33 fp32 gate tile
  __shared__ int s_xcc, s_rank;

  const int tid = threadIdx.x;
  const int bk = blockIdx.x;
  const int w = tid >> 6;
  const int lane = tid & 63;
  const int q = lane >> 4, r = lane & 15;
  const int n0 = bk * HC;

  // XCD discovery + slice-rank election
  if (tid == 0) {
    unsigned xcc;
    asm volatile("s_getreg_b32 %0, hwreg(HW_REG_XCC_ID)" : "=s"(xcc));
    xcc &= 7u;
    s_xcc = (int)xcc;
    s_rank = (int)atomicAdd(&xctr[xcc], 1u);
  }

  {
    const s16x8* src = (const s16x8*)wg + (size_t)bk * 6144;
    s16x8* dst = (s16x8*)wlds;
    for (int i = tid; i < 6144; i += 256) dst[i] = src[i];
  }

  // pointwise ownership: tid<128 -> (row=tid>>1, 4 adjacent cols)
  const int prow = tid >> 1, pcg = (tid & 1) * 4;
  float pr4[16], cr[4];
  if (tid < 128) {
#pragma unroll
    for (int g = 0; g < 4; ++g)
#pragma unroll
      for (int e = 0; e < 4; ++e)
        pr4[g * 4 + e] = pre0[bk * 2048 + prow * 32 + g * 8 + pcg + e];
#pragma unroll
    for (int e = 0; e < 4; ++e) cr[e] = cinit[prow * H + n0 + pcg + e];
  }

  __syncthreads();
  const int xcc = s_xcc;
  const int rk = s_rank;
  u16* stgx = stg + (size_t)xcc * 2 * 65536;   // this XCD's two parity buffers
  unsigned* xc = xcnt + xcc * 16;              // own 64B line per XCD

  for (int t = 0; t < LSTEPS; ++t) {
    const int par = (t - 1) & 1;               // parity of h(t-1) buffers

    // phase 1: zero gate tile (pre0 is added in the pointwise from registers)
#pragma unroll
    for (int j = 0; j < 8; ++j) {
      int i = j * 256 + tid;
      gl[(i >> 5) * GSTR + (i & 31)] = 0.f;
    }

    f32x4 acc[4][2];
#pragma unroll
    for (int mt = 0; mt < 4; ++mt) {
      f32x4 z = {0.f, 0.f, 0.f, 0.f};
      acc[mt][0] = z; acc[mt][1] = z;
    }

    // phase 2: act-part MFMAs (independent of h(t-1)) — overlap the wait
    const u16* atb = actb + (size_t)t * (B * ACTF);
#pragma unroll
    for (int kk = 0; kk < 4; ++kk) {
      const int kt = w * 4 + kk;
      const int k = kt * 32 + q * 8;
      const s16x8* wb = (const s16x8*)wlds + kt * 128;
      s16x8 bf0 = wb[lane];
      s16x8 bf1 = wb[64 + lane];
#pragma unroll
      for (int mt = 0; mt < 4; ++mt) {
        const int m = mt * 16 + r;
        s16x8 af = *(const s16x8*)(atb + m * ACTF + k);
        acc[mt][0] = __builtin_amdgcn_mfma_f32_16x16x32_bf16(af, bf0, acc[mt][0], 0, 0, 0);
        acc[mt][1] = __builtin_amdgcn_mfma_f32_16x16x32_bf16(af, bf1, acc[mt][1], 0, 0, 0);
      }
    }

    // phase 3a: wait for all h(t-1) published (single global counter, tid0 only)
    if (t && tid == 0) {
      unsigned g = 0;
      const unsigned tgt = (unsigned)(128 * t);
      while (__hip_atomic_load(scnt, __ATOMIC_RELAXED, __HIP_MEMORY_SCOPE_AGENT) < tgt) {
        __builtin_amdgcn_s_sleep(2);
        if (++g > (1u << 22)) break;   // bounded spin: wrong-answer beats hang
      }
    }
    __syncthreads();
    asm volatile("" ::: "memory");

    // phase 3b: distributed pull — this block stages slice rk (cols rk*64..+64)
    if (rk < 16) {
      const u16* hsrc = hbf + par * 65536;
      u16* sdst = stgx + par * 65536;
      const int ch0 = tid, ch1 = tid + 256;
      const int o0 = (ch0 >> 3) * 1024 + rk * 64 + (ch0 & 7) * 8;
      const int o1 = (ch1 >> 3) * 1024 + rk * 64 + (ch1 & 7) * 8;
      s16x8 v0 = ld16_coh(hsrc + o0);
      s16x8 v1 = ld16_coh(hsrc + o1);
      asm volatile("s_waitcnt vmcnt(0)" ::: "memory");
      *(s16x8*)(sdst + o0) = v0;
      *(s16x8*)(sdst + o1) = v1;
    }
    asm volatile("s_waitcnt vmcnt(0)" ::: "memory");
    __syncthreads();
    if (tid == 0) {
      atomicAdd(xc, 1u);
      unsigned g = 0;
      const unsigned tgt = (unsigned)(16 * (t + 1));
      while (__hip_atomic_load(xc, __ATOMIC_RELAXED, __HIP_MEMORY_SCOPE_AGENT) < tgt) {
        __builtin_amdgcn_s_sleep(1);
        if (++g > (1u << 22)) break;
      }
    }
    __syncthreads();
    asm volatile("buffer_inv sc0" ::: "memory");   // drop stale L1 staging lines

    // phase 4: h-part MFMAs from own-XCD L2 staging (plain cached loads)
    const u16* hstg = stgx + par * 65536;
#pragma unroll
    for (int kk = 0; kk < 8; ++kk) {
      const int kt = 16 + w * 8 + kk;
      const int k = kt * 32 + q * 8;
      const s16x8* wb = (const s16x8*)wlds + kt * 128;
      s16x8 bf0 = wb[lane];
      s16x8 bf1 = wb[64 + lane];
#pragma unroll
      for (int mt = 0; mt < 4; ++mt) {
        const int m = mt * 16 + r;
        s16x8 af = *(const s16x8*)(hstg + m * H + (k - ACTF));
        acc[mt][0] = __builtin_amdgcn_mfma_f32_16x16x32_bf16(af, bf0, acc[mt][0], 0, 0, 0);
        acc[mt][1] = __builtin_amdgcn_mfma_f32_16x16x32_bf16(af, bf1, acc[mt][1], 0, 0, 0);
      }
    }

    // phase 5: cross-wave K reduction into gate tile
#pragma unroll
    for (int mt = 0; mt < 4; ++mt) {
      const int bb2 = mt * 16 + q * 4;
#pragma unroll
      for (int T = 0; T < 2; ++T) {
        const int lc = T * 16 + r;
#pragma unroll
        for (int e = 0; e < 4; ++e)
          atomicAdd(&gl[(bb2 + e) * GSTR + lc], acc[mt][T][e]);
      }
    }
    __syncthreads();

    // phase 6: pointwise (tid<128: one row, 4 adjacent cols) + publication
    if (tid < 128) {
      float hv[4];
#pragma unroll
      for (int e = 0; e < 4; ++e) {
        const int c = pcg + e;
        float ig = sigm(gl[prow * GSTR + c] + pr4[e]);
        float fg = sigm(gl[prow * GSTR + 8 + c] + pr4[4 + e]);
        float gg = tanh_fast(gl[prow * GSTR + 16 + c] + pr4[8 + e]);
        float og = sigm(gl[prow * GSTR + 24 + c] + pr4[12 + e]);
        cr[e] = fg * cr[e] + ig * gg;
        hv[e] = og * tanh_fast(cr[e]);
      }
      f32x4 hv4; hv4[0] = hv[0]; hv4[1] = hv[1]; hv4[2] = hv[2]; hv4[3] = hv[3];
      float* oaddr = out + (size_t)t * (B * H) + prow * H + n0 + pcg;
      st16_coh(oaddr, hv4);
      if (t < LSTEPS - 1) {
        s16x4 hb; hb[0] = (short)f2bf(hv[0]); hb[1] = (short)f2bf(hv[1]);
        hb[2] = (short)f2bf(hv[2]); hb[3] = (short)f2bf(hv[3]);
        st8_coh(hbf + (t & 1) * 65536 + prow * H + n0 + pcg, __builtin_bit_cast(u64, hb));
      } else {
        float* hn = out + (size_t)LSTEPS * (B * H);
        float* cn = hn + B * H;
        f32x4 cr4; cr4[0] = cr[0]; cr4[1] = cr[1]; cr4[2] = cr[2]; cr4[3] = cr[3];
        *(f32x4*)(hn + prow * H + n0 + pcg) = hv4;
        *(f32x4*)(cn + prow * H + n0 + pcg) = cr4;
      }
    }

    // publish: drain h stores, block-join, bump the global step counter
    if (t < LSTEPS - 1) {
      asm volatile("s_waitcnt vmcnt(0)" ::: "memory");
      __syncthreads();
      if (tid == 0) atomicAdd(scnt, 1u);
    }
    __syncthreads();
  }
}

extern "C" void kernel_launch(void* const* d_in, const int* in_sizes, int n_in,
                              void* d_out, int out_size, void* d_ws, size_t ws_size,
                              hipStream_t stream) {
  const float* inf = (const float*)d_in[0];
  const float* act = (const float*)d_in[1];
  const float* h0  = (const float*)d_in[2];
  const float* cst = (const float*)d_in[3];
  const float* Wih = (const float*)d_in[4];
  const float* Whh = (const float*)d_in[5];
  const float* bih = (const float*)d_in[6];
  const float* bhh = (const float*)d_in[7];
  float* out = (float*)d_out;

  char* ws = (char*)d_ws;
  u16* actb      = (u16*)ws;                    //  8,388,608 B
  u16* wg        = (u16*)(ws + 8388608);        // 12,582,912 B
  float* pre0    = (float*)(ws + 20971520);     //  1,048,576 B
  u16* hbf       = (u16*)(ws + 22020096);       //    262,144 B (2 parity x 64x1024 bf16)
  u16* stg       = (u16*)(ws + 22282240);       //  2,097,152 B (8 XCD x 2 parity x 128KB)
  unsigned* scn  = (unsigned*)(ws + 24379392);  //         64 B
  unsigned* xcn  = (unsigned*)(ws + 24379456);  //        512 B (8 x 64B lines)
  unsigned* xct  = (unsigned*)(ws + 24379968);  //         32 B

  hipLaunchKernelGGL(k_setup, dim3(6176), dim3(256), 0, stream,
                     act, actb, Wih, Whh, wg, h0, hbf, scn, xcn, xct,
                     inf, bih, bhh, pre0);

  hipFuncSetAttribute((const void*)k_rnn, hipFuncAttributeMaxDynamicSharedMemorySize, 106752);
  hipLaunchKernelGGL(k_rnn, dim3(NB), dim3(256), 106752, stream,
                     actb, wg, pre0, cst, hbf, stg, scn, xcn, xct, out);
}